// Round 3
// baseline (164.802 us; speedup 1.0000x reference)
//
#include <hip/hip_runtime.h>
#include <hip/hip_bf16.h>
#include <stdint.h>
#include <math.h>

// Problem constants (fixed by setup_inputs)
#define BATCH 8192   // B rows of embeddings
#define DIM   2048   // D feature dim
#define KDIR  512    // K directions
#define NPTS  17     // quadrature points

typedef _Float16 half8  __attribute__((ext_vector_type(8)));
typedef float   floatx4 __attribute__((ext_vector_type(4)));

#define AS1 __attribute__((address_space(1)))
#define AS3 __attribute__((address_space(3)))

// async global->LDS, 16B per lane. LDS dest must be wave-uniform base + lane*16.
__device__ __forceinline__ void g2l16(const void* g, void* l) {
    __builtin_amdgcn_global_load_lds((AS1 void*)(uintptr_t)g, (AS3 void*)l, 16u, 0, 0u);
}

// ---------------------------------------------------------------------------
// K1: PREP (shrunk): only dir normalize+transpose -> dT (fp16) + zero pp/out.
//     gemm reads fp32 emb directly and converts during staging, so the old
//     emb fp32->fp16 pre-pass (8192 blocks, ~96 MB of traffic) is gone.
__global__ __launch_bounds__(256) void prep(const float* __restrict__ dir,
                                            _Float16* __restrict__ dT,
                                            float* __restrict__ pp,
                                            float* __restrict__ out) {
    const int b = blockIdx.x;   // 0..63
    const int t = threadIdx.x;
    if (b == 0) {
        ((floatx4*)pp)[t] = floatx4{0.f, 0.f, 0.f, 0.f};   // 1024 floats
        if (t == 0) out[0] = 0.f;
    }
    const int k0 = b * 8;
    __shared__ _Float16 sv[8][2052];    // [col][row] staged values (fp16)
    __shared__ float    sred[8][32];
    __shared__ float    sinv[8];
    const int g  = t >> 3;     // 0..31 row-group
    const int cl = t & 7;      // col within 8
    float ss = 0.f;
    #pragma unroll 8
    for (int it = 0; it < 64; ++it) {
        const int r = it * 32 + g;
        float v = dir[(size_t)r * KDIR + k0 + cl];   // 8 lanes = 32B contiguous
        sv[cl][r] = (_Float16)v;
        ss = fmaf(v, v, ss);
    }
    sred[cl][g] = ss;
    __syncthreads();
    if (t < 8) {
        float s = 0.f;
        #pragma unroll
        for (int gg = 0; gg < 32; ++gg) s += sred[t][gg];
        sinv[t] = 1.0f / fmaxf(sqrtf(s), 1e-12f);
    }
    __syncthreads();
    // pass 2: coalesced half8 writes of dT rows
    const int c2 = t >> 5;     // 0..7 col
    const int p  = t & 31;
    const float inv = sinv[c2];
    #pragma unroll
    for (int it2 = 0; it2 < 8; ++it2) {
        const int i0 = p * 8 + it2 * 256;
        half8 h;
        #pragma unroll
        for (int e = 0; e < 8; ++e) h[e] = (_Float16)((float)sv[c2][i0 + e] * inv);
        *(half8*)(dT + (size_t)(k0 + c2) * DIM + i0) = h;
    }
}

// ---------------------------------------------------------------------------
// K2: fp16 MFMA GEMM, fp32 A read directly (no A16 round-trip).
//   - 512 threads = 8 waves = 2 waves/SIMD; wave tile 64x32, acc[4][2].
//   - XCD-ownership remap: d = bx + 64*by; xcd = d&7 owns 8 row-panels x all
//     4 col-blocks -> each A-panel consumed inside one XCD, HBM-read once.
//   - A reg-staged: 4x global_load_dwordx4 issued early; cvt fp32->fp16 +
//     2x swizzled ds_write_b128 after the MFMA cluster (T14 split).
//   - ORDER PIN: empty asm-with-memory-clobber between LOADA and ISSUEB so
//     the vmem queue is deterministically [A x4 older, B x2 newer]. Without
//     it the compiler may interleave the plain loads with the g2l16
//     intrinsics and vmcnt(2) would retire B instead of A -> WRITEA would
//     convert undrained registers (silent corruption).
//   - vmcnt(6) at loop top drains only B(it); vmcnt(2) post-MFMA drains only
//     A(it+1); B(it+1) stays in flight across the barrier (counted-vmcnt).
//   - A LDS [2][128][64] halfs, XOR swizzle (byte ^= (row&7)<<4) on BOTH
//     write and read; linear 128B rows would be a 16-way ds_read conflict.
//   - B: g2l16 into linear [stage][panel][128x32] (unchanged from the
//     measured 45.6us kernel).
__global__ __launch_bounds__(512) void gemm16(const float* __restrict__ A,
                                              const _Float16* __restrict__ Bt,
                                              _Float16* __restrict__ C,
                                              float* __restrict__ pp) {
    __shared__ __align__(16) _Float16 sA[2][128 * 64];   // 16 KB per stage
    __shared__ __align__(16) _Float16 sB[2][2][128 * 32];

    const int tid  = threadIdx.x;
    const int lane = tid & 63;
    const int wave = tid >> 6;     // 0..7
    const int wm = wave & 1;       // 64-row half
    const int wn = wave >> 1;      // 0..3 32-col quarter

    // XCD-ownership remap (grid (64,4) = 256 blocks, multiple of 8: bijective)
    const int d    = blockIdx.x + 64 * blockIdx.y;
    const int xcd  = d & 7;
    const int slot = d >> 3;                 // 0..31
    const int bx   = (slot >> 2) * 8 + xcd;  // 0..63 row-panel
    const int by   = slot & 3;               // 0..3  col-block
    const int tm = bx * 128;
    const int tn = by * 128;

    // A staging addressing: 4 threads per row, 16 consecutive floats each
    const int arow  = tid >> 2;            // 0..127
    const int acolf = (tid & 3) * 16;      // float col base
    const float* baseA = A + (size_t)(tm + arow) * DIM + acolf;
    const int asw   = (arow & 7) << 4;     // write-side swizzle
    const int aoff0 = arow * 128 + (((tid & 3) * 32) ^ asw);
    const int aoff1 = arow * 128 + ((((tid & 3) * 32) + 16) ^ asw);
    char* const aBase = (char*)&sA[0][0];  // stage stride 16384 B

    // B staging (global_load_lds): linear, lane-order == LDS order
    const int srow = tid >> 2;
    const int scol = (tid & 3) * 8;
    const _Float16* baseB = Bt + (size_t)(tn + srow) * DIM + scol;

    floatx4 rA0, rA1, rA2, rA3;

#define LOADA(IT) do {                                                        \
        const float* pa = baseA + (IT) * 64;                                  \
        rA0 = *(const floatx4*)(pa);      rA1 = *(const floatx4*)(pa + 4);    \
        rA2 = *(const floatx4*)(pa + 8);  rA3 = *(const floatx4*)(pa + 12);   \
        asm volatile("" ::: "memory");  /* pin: A-loads BEFORE B g2l16s */    \
    } while (0)

#define ISSUEB(IT, ST) do {                                                   \
        const _Float16* pb = baseB + (IT) * 64;                               \
        g2l16(pb,      (char*)&sB[ST][0][0] + tid * 16);                      \
        g2l16(pb + 32, (char*)&sB[ST][1][0] + tid * 16);                      \
    } while (0)

#define WRITEA(ST) do {                                                       \
        half8 h0, h1;                                                         \
        h0[0] = (_Float16)rA0[0]; h0[1] = (_Float16)rA0[1];                   \
        h0[2] = (_Float16)rA0[2]; h0[3] = (_Float16)rA0[3];                   \
        h0[4] = (_Float16)rA1[0]; h0[5] = (_Float16)rA1[1];                   \
        h0[6] = (_Float16)rA1[2]; h0[7] = (_Float16)rA1[3];                   \
        h1[0] = (_Float16)rA2[0]; h1[1] = (_Float16)rA2[1];                   \
        h1[2] = (_Float16)rA2[2]; h1[3] = (_Float16)rA2[3];                   \
        h1[4] = (_Float16)rA3[0]; h1[5] = (_Float16)rA3[1];                   \
        h1[6] = (_Float16)rA3[2]; h1[7] = (_Float16)rA3[3];                   \
        *(half8*)(aBase + (ST) * 16384 + aoff0) = h0;                         \
        *(half8*)(aBase + (ST) * 16384 + aoff1) = h1;                         \
    } while (0)

    const floatx4 zero = {0.f, 0.f, 0.f, 0.f};
    floatx4 acc[4][2];
    #pragma unroll
    for (int i = 0; i < 4; ++i)
        #pragma unroll
        for (int j = 0; j < 2; ++j) acc[i][j] = zero;

    const int mrow  = lane & 15;
    const int kk    = (lane >> 4) * 8;      // half-index 0/8/16/24
    const int asw_r = (mrow & 7) << 4;      // read-side swizzle ((row&7)==(mrow&7))
    const int akb0  = (kk * 2) ^ asw_r;     // a0 byte-in-row (k 0..31)
    const int akb1  = (64 + kk * 2) ^ asw_r;// a1 byte-in-row (k 32..63)

    // prologue: stage 0. Queue after issues: [A(0) x4, B(0) x2].
    LOADA(0);
    ISSUEB(0, 0);
    asm volatile("s_waitcnt vmcnt(2)" ::: "memory");   // A(0) regs ready
    WRITEA(0);
    asm volatile("s_waitcnt lgkmcnt(0)" ::: "memory"); // own A(0) ds_writes done

    const int NIT = DIM / 64;                      // 32
    for (int it = 0; it < NIT; ++it) {
        const int s = it & 1;
        if (it + 1 < NIT) {
            LOADA(it + 1);                         // +4 vmem (oldest of new)
            ISSUEB(it + 1, s ^ 1);                 // +2 vmem (newest)
            // outstanding: [B(it) x2, A(it+1) x4, B(it+1) x2] = 8
            asm volatile("s_waitcnt vmcnt(6)" ::: "memory");  // drain B(it) only
        } else {
            asm volatile("s_waitcnt vmcnt(0)" ::: "memory");
        }
        asm volatile("s_barrier" ::: "memory");    // stage s fully visible

        half8 a0[4], a1[4], b0[2], b1[2];
        #pragma unroll
        for (int f = 0; f < 4; ++f) {
            const int row = wm * 64 + f * 16 + mrow;
            a0[f] = *(const half8*)(aBase + s * 16384 + row * 128 + akb0);
            a1[f] = *(const half8*)(aBase + s * 16384 + row * 128 + akb1);
        }
        #pragma unroll
        for (int f = 0; f < 2; ++f) {
            b0[f] = *(const half8*)(&sB[s][0][(size_t)(wn * 32 + f * 16 + mrow) * 32 + kk]);
            b1[f] = *(const half8*)(&sB[s][1][(size_t)(wn * 32 + f * 16 + mrow) * 32 + kk]);
        }
        #pragma unroll
        for (int i = 0; i < 4; ++i)
            #pragma unroll
            for (int j = 0; j < 2; ++j) {
                acc[i][j] = __builtin_amdgcn_mfma_f32_16x16x32_f16(a0[i], b0[j], acc[i][j], 0, 0, 0);
                acc[i][j] = __builtin_amdgcn_mfma_f32_16x16x32_f16(a1[i], b1[j], acc[i][j], 0, 0, 0);
            }

        if (it + 1 < NIT) {
            // outstanding: [A(it+1) x4, B(it+1) x2]; drain A only.
            asm volatile("s_waitcnt vmcnt(2)" ::: "memory");
            WRITEA(s ^ 1);                         // B(it+1) still in flight
        }
        asm volatile("s_waitcnt lgkmcnt(0)" ::: "memory");  // reads(s)+writes(s^1) done
        asm volatile("s_barrier" ::: "memory");
    }
#undef LOADA
#undef ISSUEB
#undef WRITEA

    // C/D layout: col = lane&15, row = (lane>>4)*4 + reg. fp16 stores.
    const int r0 = (lane >> 4) * 4;
    const int cn = lane & 15;
    #pragma unroll
    for (int i = 0; i < 4; ++i) {
        #pragma unroll
        for (int j = 0; j < 2; ++j) {
            const int row = tm + wm * 64 + i * 16 + r0;
            const int col = tn + wn * 32 + j * 16 + cn;
            #pragma unroll
            for (int r = 0; r < 4; ++r)
                C[(size_t)(row + r) * KDIR + col] = (_Float16)acc[i][j][r];
        }
    }

    // fused column stats (fp32 acc values); per wave: 64 rows per column
    #pragma unroll
    for (int j = 0; j < 2; ++j) {
        float s = 0.f, q = 0.f;
        #pragma unroll
        for (int i = 0; i < 4; ++i)
            #pragma unroll
            for (int r = 0; r < 4; ++r) {
                float v = acc[i][j][r];
                s += v;
                q = fmaf(v, v, q);
            }
        s += __shfl_down(s, 32, 64); q += __shfl_down(q, 32, 64);
        s += __shfl_down(s, 16, 64); q += __shfl_down(q, 16, 64);
        if (lane < 16) {
            const int col = tn + wn * 32 + j * 16 + lane;
            atomicAdd(&pp[col], s);
            atomicAdd(&pp[KDIR + col], q);
        }
    }
}

// ---------------------------------------------------------------------------
// K3: ECF partials from fp16 proj; mu/isd inline from pp; Chebyshev recurrence.
__global__ __launch_bounds__(256) void ecf_p1(const _Float16* __restrict__ proj,
                                              const float* __restrict__ pp,
                                              float* __restrict__ pecf) {
    const int ch = blockIdx.x >> 1;                      // 0..255
    const int c  = (blockIdx.x & 1) * 256 + threadIdx.x; // 0..511
    const double s_  = (double)pp[c];
    const double s2_ = (double)pp[KDIR + c];
    const double mm  = s_ / (double)BATCH;
    const double var = (s2_ - (double)BATCH * mm * mm) / (double)(BATCH - 1);
    const float m   = (float)mm;
    const float sdi = (float)(1.0 / (sqrt(var) + 1e-8));

    float cr[NPTS], ci[NPTS];
    #pragma unroll
    for (int i = 0; i < NPTS; ++i) { cr[i] = 0.f; ci[i] = 0.f; }
    const _Float16* p = proj + (size_t)(ch * 32) * KDIR + c;
    #pragma unroll 8
    for (int r = 0; r < 32; ++r) {
        float z = ((float)p[(size_t)r * KDIR] - m) * sdi;
        float a = z * (2.0f / 17.0f);                    // t_1 * z
        float s1, c1;
        __sincosf(a, &s1, &c1);
        const float tc = 2.0f * c1;
        float cm = 1.0f, sm = 0.0f;
        float ck = c1,  sk = s1;
        cr[0] += ck; ci[0] += sk;
        #pragma unroll
        for (int k = 1; k < NPTS; ++k) {
            float cn_ = fmaf(tc, ck, -cm);
            float sn_ = fmaf(tc, sk, -sm);
            cm = ck; sm = sk;
            ck = cn_; sk = sn_;
            cr[k] += ck; ci[k] += sk;
        }
    }
    #pragma unroll
    for (int i = 0; i < NPTS; ++i) {
        pecf[(size_t)((ch * NPTS + i) * 2 + 0) * KDIR + c] = cr[i];
        pecf[(size_t)((ch * NPTS + i) * 2 + 1) * KDIR + c] = ci[i];
    }
}

// K4: chunk reduce, one latency round: 544 blocks = 17 i x 16 grp x 2 halves.
__global__ __launch_bounds__(256) void ecf_p2a(const float* __restrict__ pecf,
                                               double* __restrict__ pec2) {
    const int b = blockIdx.x;
    const int i = b >> 5;                 // 0..16
    const int r = b & 31;
    const int g = r >> 1;                 // 0..15 (16 chunks each)
    const int half = r & 1;
    const int c = half * 256 + threadIdx.x;
    double sc = 0.0, ss = 0.0;
    #pragma unroll
    for (int k = 0; k < 16; ++k) {
        const int ch = g * 16 + k;
        sc += (double)pecf[(size_t)((ch * NPTS + i) * 2 + 0) * KDIR + c];
        ss += (double)pecf[(size_t)((ch * NPTS + i) * 2 + 1) * KDIR + c];
    }
    pec2[(size_t)((i * 16 + g) * 2 + 0) * KDIR + c] = sc;
    pec2[(size_t)((i * 16 + g) * 2 + 1) * KDIR + c] = ss;
}

// K5: finish: sum 16 groups, integrand, block-reduce, atomic.
__global__ __launch_bounds__(256) void ecf_p2b(const double* __restrict__ pec2,
                                               float* __restrict__ out) {
    const int i = blockIdx.x >> 1;
    const int c = (blockIdx.x & 1) * 256 + threadIdx.x;
    double sc = 0.0, ss = 0.0;
    #pragma unroll
    for (int g = 0; g < 16; ++g) {
        sc += pec2[(size_t)((i * 16 + g) * 2 + 0) * KDIR + c];
        ss += pec2[(size_t)((i * 16 + g) * 2 + 1) * KDIR + c];
    }
    const double R = sc / (double)BATCH;
    const double I = ss / (double)BATCH;
    const double t = (2.0 / 17.0) * (double)(i + 1);
    const double tau = exp(-0.5 * t * t);
    const double w = (i == 0 || i == NPTS - 1) ? (1.0 / 17.0) : (2.0 / 17.0);
    const double dR = R - tau;
    double contrib = w * (dR * dR + I * I) / (double)KDIR;

    __shared__ double red[256];
    red[threadIdx.x] = contrib;
    __syncthreads();
    for (int s = 128; s > 0; s >>= 1) {
        if (threadIdx.x < s) red[threadIdx.x] += red[threadIdx.x + s];
        __syncthreads();
    }
    if (threadIdx.x == 0) atomicAdd(out, (float)red[0]);
}

// ---------------------------------------------------------------------------
extern "C" void kernel_launch(void* const* d_in, const int* in_sizes, int n_in,
                              void* d_out, int out_size, void* d_ws, size_t ws_size,
                              hipStream_t stream) {
    const float* emb = (const float*)d_in[0];   // (8192, 2048) fp32
    const float* dir = (const float*)d_in[1];   // (2048, 512) fp32
    float* out = (float*)d_out;

    char* ws = (char*)d_ws;
    float*    pecf = (float*)   (ws + 0);               // 17,825,792 B
    double*   pec2 = (double*)  (ws + 17825792);        //  2,228,224 B
    _Float16* dT   = (_Float16*)(ws + 33554432);        //  2,097,152 B
    _Float16* proj = (_Float16*)(ws + 35651584);        //  8,388,608 B
    float*    pp   = (float*)   (ws + 44040192);        //      4,096 B

    prep<<<64, 256, 0, stream>>>(dir, dT, pp, out);
    gemm16<<<dim3(BATCH / 128, KDIR / 128), 512, 0, stream>>>(emb, dT, proj, pp);
    ecf_p1<<<512, 256, 0, stream>>>(proj, pp, pecf);
    ecf_p2a<<<544, 256, 0, stream>>>(pecf, pec2);
    ecf_p2b<<<34, 256, 0, stream>>>(pec2, out);
}